// Round 9
// baseline (73.077 us; speedup 1.0000x reference)
//
#include <hip/hip_runtime.h>

// ---- problem constants ----
#define PS   10
#define KNN  7
#define WSZ  29
#define RR   14
#define IH   96
#define IW   96
#define CH   16
#define CE   8
#define HH   98            // query grid (after pad1)
#define QN   (HH*HH)       // 9604 queries
#define ND   (WSZ*WSZ)     // 841 displacements
#define XTW  124           // padded x (bf16): coords [-14,109]
#define XTP  14
#define YEW  107
#define YEH  112
#define XEW  144
#define XEH  144
#define QP   9800          // dist plane pitch (98 rows x 100)

// ---- ws layout (float units) ----
#define OFF_CV   8241856ull                 // align64(841*9800); candidates QN*4*8
#define OFF_CI   (OFF_CV + 307328ull)
#define OFF_XT   (OFF_CI + 307328ull)       // bf16 x: 124*124*16 ushort = 123008 fl
#define OFF_YEP  (OFF_XT + 123072ull)
#define OFF_XEP  (OFF_YEP + 95872ull)
// end = OFF_XEP + 165888 = 9,241,344 floats = 37 MB

__device__ __forceinline__ int imin(int a, int b){ return a<b?a:b; }
__device__ __forceinline__ int imax(int a, int b){ return a>b?a:b; }
__device__ __forceinline__ unsigned short f2bf(float f){
    unsigned u = __float_as_uint(f);
    return (unsigned short)((u + 0x7fffu + ((u >> 16) & 1u)) >> 16);
}

// ---- K0: pack x -> bf16 xTb[124][124][16]; ye -> yeP[112][107][8]; xe -> xeP[144][144][8]
__global__ __launch_bounds__(256) void k_prep(const float* __restrict__ x,
                                              const float* __restrict__ xe,
                                              const float* __restrict__ ye,
                                              unsigned short* __restrict__ xTb,
                                              float* __restrict__ xeP,
                                              float* __restrict__ yeP) {
    int t = blockIdx.x*256 + threadIdx.x;
    if (t < XTW*XTW) {
        int u = t / XTW, v = t % XTW;
        int ui = u - XTP, vi = v - XTP;
        bool inb = ((unsigned)ui < (unsigned)IH) && ((unsigned)vi < (unsigned)IW);
        int off = inb ? (ui*IW + vi) : 0;
        unsigned d[8];
        #pragma unroll
        for (int j = 0; j < 8; ++j) {
            float a = inb ? x[(2*j+0)*IH*IW + off] : 0.f;
            float b = inb ? x[(2*j+1)*IH*IW + off] : 0.f;
            d[j] = (unsigned)f2bf(a) | ((unsigned)f2bf(b) << 16);
        }
        uint4* dst = (uint4*)(xTb + (size_t)t*CH);
        dst[0] = make_uint4(d[0], d[1], d[2], d[3]);
        dst[1] = make_uint4(d[4], d[5], d[6], d[7]);
        return;
    }
    t -= XTW*XTW;
    if (t < YEH*YEW) {
        int i = t / YEW, j = t % YEW;
        bool inb = ((unsigned)(i-6) < (unsigned)IH) && ((unsigned)(j-6) < (unsigned)IW);
        int off = inb ? ((i-6)*IW + (j-6)) : 0;
        float4* dst = (float4*)(yeP + (size_t)t*CE);
        #pragma unroll
        for (int c4 = 0; c4 < 2; ++c4) {
            float4 val;
            val.x = inb ? ye[(c4*4+0)*IH*IW + off] : 0.f;
            val.y = inb ? ye[(c4*4+1)*IH*IW + off] : 0.f;
            val.z = inb ? ye[(c4*4+2)*IH*IW + off] : 0.f;
            val.w = inb ? ye[(c4*4+3)*IH*IW + off] : 0.f;
            dst[c4] = val;
        }
        return;
    }
    t -= YEH*YEW;
    if (t < XEH*XEW) {
        int i = t / XEW, j = t % XEW;
        bool inb = ((unsigned)(i-20) < (unsigned)IH) && ((unsigned)(j-20) < (unsigned)IW);
        int off = inb ? ((i-20)*IW + (j-20)) : 0;
        float4* dst = (float4*)(xeP + (size_t)t*CE);
        #pragma unroll
        for (int c4 = 0; c4 < 2; ++c4) {
            float4 val;
            val.x = inb ? xe[(c4*4+0)*IH*IW + off] : 0.f;
            val.y = inb ? xe[(c4*4+1)*IH*IW + off] : 0.f;
            val.z = inb ? xe[(c4*4+2)*IH*IW + off] : 0.f;
            val.w = inb ? xe[(c4*4+3)*IH*IW + off] : 0.f;
            dst[c4] = val;
        }
    }
}

// ---- K1: distances, barrier-free wave-private, 25-row strips ----
// block = (dy-group of 4, dx, 25-row strip). grid = 8*29*4 = 928, 128 thr.
__global__ __launch_bounds__(128, 4) void k_dist(const float* __restrict__ xeP,
                                                 const float* __restrict__ yeP,
                                                 float* __restrict__ dist) {
    __shared__ float cs[2][4][72];       // 2.3 KB, wave-private halves

    int b     = blockIdx.x;
    int dx_i  = b % 29;
    int rem   = b / 29;
    int strip = rem & 3;
    int dyg   = rem >> 2;                // 0..7
    int y0s   = strip * 25;
    int tid   = threadIdx.x;
    int wid   = tid >> 6;
    int lane  = tid & 63;
    int col   = wid ? (43 + lane) : lane;
    int widx  = lane + (wid ? 3 : 0);

    int nun   = wid ? 12 : 13;
    int dyi_c = imin(lane / nun, 3);
    int u     = lane - dyi_c * nun;
    bool cact = lane < nun * 4;
    int x0u   = wid ? (52 + 4*u) : (4*u);
    bool full4 = (wid == 0) || (u < 11);
    const float* rdp = &cs[wid][dyi_c][ wid ? (12 + 4*u) : (4*u) ];
    int plane = dyg*4 + dyi_c;
    bool plane_ok = cact && (plane <= 28);
    int dy_c  = plane - 14;
    int dx    = dx_i - 14;
    bool selfd = (dy_c == 0) && (dx == 0);
    bool okx0 = (unsigned)(x0u+0+dx) < 98u;
    bool okx1 = (unsigned)(x0u+1+dx) < 98u;
    bool okx2 = (unsigned)(x0u+2+dx) < 98u;
    bool okx3 = (unsigned)(x0u+3+dx) < 98u;
    float* dout = dist + (size_t)(imin(plane,28)*29 + dx_i)*QP + x0u;

    const size_t xstep = (size_t)XEW*CE, ystep = (size_t)YEW*CE;
    const float* xload = xeP + ((size_t)(y0s + dyg*4)*XEW + (col + dx_i))*CE;
    const float* yload = yeP + ((size_t)y0s*YEW + col)*CE;

    float4 xr[5][2];
    #pragma unroll
    for (int r = 0; r < 4; ++r) {
        xr[r][0] = ((const float4*)xload)[0];
        xr[r][1] = ((const float4*)xload)[1];
        xload += xstep;
    }
    float wsum[4] = {0.f,0.f,0.f,0.f};
    float hist[4][10];

#define DSTEP(S) { \
    float4 xna = ((const float4*)xload)[0]; \
    float4 xnb = ((const float4*)xload)[1]; \
    xload += xstep; \
    float4 ya  = ((const float4*)yload)[0]; \
    float4 yb  = ((const float4*)yload)[1]; \
    yload += ystep; \
    xr[(S+4)%5][0] = xna; xr[(S+4)%5][1] = xnb; \
    _Pragma("unroll") \
    for (int dyi = 0; dyi < 4; ++dyi) { \
        float4 xa = xr[(S+dyi)%5][0]; \
        float4 xb = xr[(S+dyi)%5][1]; \
        float d0=ya.x-xa.x, d1=ya.y-xa.y, d2=ya.z-xa.z, d3=ya.w-xa.w; \
        float d4=yb.x-xb.x, d5=yb.y-xb.y, d6=yb.z-xb.z, d7=yb.w-xb.w; \
        float a = d0*d0; \
        a=fmaf(d1,d1,a); a=fmaf(d2,d2,a); a=fmaf(d3,d3,a); \
        a=fmaf(d4,d4,a); a=fmaf(d5,d5,a); a=fmaf(d6,d6,a); \
        a=fmaf(d7,d7,a); \
        float w = wsum[dyi] + a; \
        if ((S) >= 10) w -= hist[dyi][(S)%10]; \
        wsum[dyi] = w; \
        hist[dyi][(S)%10] = a; \
        cs[wid][dyi][widx] = w; \
    } \
    if ((S) >= 9 && plane_ok) { \
        int y0 = y0s + (S) - 9; \
        if (y0 < 98) { \
            float v0=rdp[0], v1=rdp[1], v2=rdp[2], v3=rdp[3]; \
            float v4=rdp[4], v5=rdp[5], v6=rdp[6], v7=rdp[7]; \
            float v8=rdp[8], v9=rdp[9], v10=rdp[10], v11=rdp[11], v12=rdp[12]; \
            float s0 = ((v0+v1)+(v2+v3)) + ((v4+v5)+(v6+v7)) + (v8+v9); \
            float s1 = s0 - v0 + v10; \
            float s2 = s1 - v1 + v11; \
            float s3 = s2 - v2 + v12; \
            bool okr = ((unsigned)(y0 + dy_c) < 98u) && !selfd; \
            float4 o; \
            o.x = (okr && okx0) ? s0 : 1e10f; \
            o.y = (okr && okx1) ? s1 : 1e10f; \
            o.z = (okr && okx2) ? s2 : 1e10f; \
            o.w = (okr && okx3) ? s3 : 1e10f; \
            if (full4) *(float4*)(dout + y0*100) = o; \
            else       *(float2*)(dout + y0*100) = make_float2(o.x, o.y); \
        } \
    } \
}

    DSTEP(0)  DSTEP(1)  DSTEP(2)  DSTEP(3)  DSTEP(4)
    DSTEP(5)  DSTEP(6)  DSTEP(7)  DSTEP(8)  DSTEP(9)
    DSTEP(10) DSTEP(11) DSTEP(12) DSTEP(13) DSTEP(14)
    DSTEP(15) DSTEP(16) DSTEP(17) DSTEP(18) DSTEP(19)
    DSTEP(20) DSTEP(21) DSTEP(22) DSTEP(23) DSTEP(24)
    DSTEP(25) DSTEP(26) DSTEP(27) DSTEP(28) DSTEP(29)
    DSTEP(30) DSTEP(31) DSTEP(32) DSTEP(33)
#undef DSTEP
}

// ---- K2: stage-A top-7 per (query, displacement-quarter). grid 151*4 ----
__global__ __launch_bounds__(256) void k_topkA(const float* __restrict__ dist,
                                               float* __restrict__ cv, int* __restrict__ ci) {
    __shared__ float lv[3*64*8];
    __shared__ int   lix[3*64*8];
    int wv = threadIdx.x >> 6, ln = threadIdx.x & 63;
    int qb = blockIdx.x % 151;
    int rg = blockIdx.x / 151;           // 0..3
    int q  = qb*64 + ln;
    int qq = q < QN ? q : QN-1;
    int y0 = qq / 98, x0 = qq - y0*98;
    int off = y0*100 + x0;

    int rbase = rg*210 + (rg > 0 ? 1 : 0);   // 0,211,421,631
    int ndr   = (rg == 0) ? 211 : 210;
    int s0 = rbase + wv*53;
    int s1 = imin(rbase + ndr, s0 + 53);

    float ld[KNN]; int li[KNN];
    #pragma unroll
    for (int k = 0; k < KNN; ++k) { ld[k] = 1e30f; li[k] = -1; }

    auto INS = [&](float v, int dsp) {
        float cvv = v; int cii = dsp;
        #pragma unroll
        for (int k = 0; k < KNN; ++k) {
            bool sw = cvv < ld[k];
            float tf = ld[k]; int ti = li[k];
            ld[k] = sw ? cvv : tf;  li[k] = sw ? cii : ti;
            cvv   = sw ? tf : cvv;  cii   = sw ? ti : cii;
        }
    };

    #pragma unroll 4
    for (int dd = s0; dd < s1; ++dd)
        INS(dist[(size_t)dd*QP + off], dd);

    if (wv) {
        int bse = ((wv-1)*64 + ln)*8;
        #pragma unroll
        for (int r = 0; r < KNN; ++r) { lv[bse+r] = ld[r]; lix[bse+r] = li[r]; }
    }
    __syncthreads();
    if (wv == 0 && q < QN) {
        #pragma unroll
        for (int w = 0; w < 3; ++w) {
            int bse = (w*64 + ln)*8;
            #pragma unroll
            for (int r = 0; r < KNN; ++r) INS(lv[bse+r], lix[bse+r]);
        }
        #pragma unroll
        for (int r = 0; r < KNN; ++r) {
            cv[(q*4 + rg)*8 + r] = ld[r];
            ci[(q*4 + rg)*8 + r] = li[r];
        }
    }
}

// ---- K3: merge+softmax staging, then bf16 gather aggregation ----
// block = 4x4 pixel tile, 256 thr = 8 (oy,ox)-groups x (16 px x 2 ch-halves)
__global__ __launch_bounds__(256) void k_agg(const float* __restrict__ x,
                                             const unsigned short* __restrict__ xTb,
                                             const float* __restrict__ cv,
                                             const int* __restrict__ ci,
                                             float* __restrict__ out) {
    __shared__ float2 lw[169*7];      // (w, delta_ushort_units) per halo query
    __shared__ float  red[7][8][32];  // og 1..7 partials, conflict-free layout
    int tid = threadIdx.x;
    int tb  = blockIdx.x;
    int ai0 = (tb / 24) * 4, bi0 = (tb % 24) * 4;

    // stage: per halo query merge 28 candidates -> top7 -> softmax -> (w, dl)
    if (tid < 169) {
        int lqi = tid / 13, lqj = tid - lqi*13;
        int qi = ai0 - 3 + lqi, qj = bi0 - 3 + lqj;
        bool ok = ((unsigned)qi < 98u) && ((unsigned)qj < 98u);
        float ld[KNN]; int li[KNN];
        #pragma unroll
        for (int k = 0; k < KNN; ++k) { ld[k] = 1e30f; li[k] = -1; }
        if (ok) {
            int q = qi*98 + qj;
            #pragma unroll
            for (int rg = 0; rg < 4; ++rg) {
                #pragma unroll
                for (int r = 0; r < KNN; ++r) {
                    float v  = cv[(q*4 + rg)*8 + r];
                    int dsp  = ci[(q*4 + rg)*8 + r];
                    float cvv = v; int cii = dsp;
                    #pragma unroll
                    for (int k = 0; k < KNN; ++k) {
                        bool sw = cvv < ld[k];
                        float tf = ld[k]; int ti = li[k];
                        ld[k] = sw ? cvv : tf;  li[k] = sw ? cii : ti;
                        cvv   = sw ? tf : cvv;  cii   = sw ? ti : cii;
                    }
                }
            }
            float e[KNN]; float ssum = 0.f;
            #pragma unroll
            for (int r = 0; r < KNN; ++r) { e[r] = __expf(ld[0] - ld[r]); ssum += e[r]; }
            float inv = 1.f / ssum;
            #pragma unroll
            for (int r = 0; r < KNN; ++r) {
                int dsp = li[r];
                int dyk = dsp / WSZ - RR, dxk = dsp % WSZ - RR;
                lw[tid*7 + r] = make_float2(e[r]*inv,
                                            __int_as_float((dyk*XTW + dxk)*CH));
            }
        } else {
            #pragma unroll
            for (int r = 0; r < KNN; ++r) lw[tid*7 + r] = make_float2(0.f, 0.f);
        }
    }
    __syncthreads();

    int og   = tid >> 5;          // 0..7 position groups
    int rem  = tid & 31;
    int half = rem & 1;           // channel half (0: ch0-7, 1: ch8-15)
    int pl   = rem >> 1;          // 0..15 pixel
    int py   = pl >> 2, px = pl & 3;
    int ai = ai0 + py, bi = bi0 + px;
    int baseu = ((ai + XTP)*XTW + (bi + XTP))*CH + half*8;

    float acc[8] = {0.f,0.f,0.f,0.f,0.f,0.f,0.f,0.f};
    #pragma unroll
    for (int c = 0; c < 13; ++c) {
        int u = og*13 + c;
        if (u >= 100) break;
        int oy = u / 10, ox = u - oy*10;
        int lq = (py + 9 - oy)*13 + (px + 9 - ox);
        const float2* f2p = lw + lq*7;
        #pragma unroll
        for (int k = 0; k < KNN; ++k) {
            float2 wd = f2p[k];
            float w = wd.x;
            int dl = __float_as_int(wd.y);
            const uint4 g = *(const uint4*)(xTb + baseu + dl);
            acc[0] = fmaf(w, __uint_as_float(g.x << 16),          acc[0]);
            acc[1] = fmaf(w, __uint_as_float(g.x & 0xffff0000u),  acc[1]);
            acc[2] = fmaf(w, __uint_as_float(g.y << 16),          acc[2]);
            acc[3] = fmaf(w, __uint_as_float(g.y & 0xffff0000u),  acc[3]);
            acc[4] = fmaf(w, __uint_as_float(g.z << 16),          acc[4]);
            acc[5] = fmaf(w, __uint_as_float(g.z & 0xffff0000u),  acc[5]);
            acc[6] = fmaf(w, __uint_as_float(g.w << 16),          acc[6]);
            acc[7] = fmaf(w, __uint_as_float(g.w & 0xffff0000u),  acc[7]);
        }
    }

    if (og) {
        #pragma unroll
        for (int c = 0; c < 8; ++c) red[og-1][c][rem] = acc[c];
    }
    __syncthreads();
    if (og == 0) {
        #pragma unroll
        for (int w = 0; w < 7; ++w)
            #pragma unroll
            for (int c = 0; c < 8; ++c) acc[c] += red[w][c][rem];

        int i = ai + 6, j = bi + 6;
        float cr = (float)(imin(i, 97) - imax(i - 9, 0) + 1);
        float cc = (float)(imin(j, 97) - imax(j - 9, 0) + 1);
        float inv = 1.f / (cr * cc);
        int p = ai*IW + bi;
        #pragma unroll
        for (int c = 0; c < 8; ++c) {
            int ch = half*8 + c;
            float xv = x[ch*IH*IW + p];           // exact f32 copy of y
            out[ch*IH*IW + p] = xv;
            out[(16 + ch)*IH*IW + p] = acc[c]*inv - xv;
        }
    }
}

extern "C" void kernel_launch(void* const* d_in, const int* in_sizes, int n_in,
                              void* d_out, int out_size, void* d_ws, size_t ws_size,
                              hipStream_t stream) {
    const float* x  = (const float*)d_in[0];
    const float* xe = (const float*)d_in[1];
    const float* ye = (const float*)d_in[2];
    float* out = (float*)d_out;
    float* ws  = (float*)d_ws;

    float* dist = ws;
    float* cv   = ws + OFF_CV;
    int*   ci   = (int*)(ws + OFF_CI);
    unsigned short* xTb = (unsigned short*)(ws + OFF_XT);
    float* yeP  = ws + OFF_YEP;
    float* xeP  = ws + OFF_XEP;

    {
        int total = XTW*XTW + YEH*YEW + XEH*XEW;
        hipLaunchKernelGGL(k_prep, dim3((total + 255)/256), dim3(256), 0, stream,
                           x, xe, ye, xTb, xeP, yeP);
    }
    hipLaunchKernelGGL(k_dist,  dim3(8*29*4), dim3(128), 0, stream, xeP, yeP, dist);
    hipLaunchKernelGGL(k_topkA, dim3(151*4), dim3(256), 0, stream, dist, cv, ci);
    hipLaunchKernelGGL(k_agg,   dim3(24*24), dim3(256), 0, stream, x, xTb, cv, ci, out);
}

// Round 10
// 72.597 us; speedup vs baseline: 1.0066x; 1.0066x over previous
//
#include <hip/hip_runtime.h>

// ---- problem constants ----
#define PS   10
#define KNN  7
#define WSZ  29
#define RR   14
#define IH   96
#define IW   96
#define CH   16
#define CE   8
#define HH   98            // query grid (after pad1)
#define QN   (HH*HH)       // 9604 queries
#define ND   (WSZ*WSZ)     // 841 displacements
#define XTW  124           // padded x (bf16): coords [-14,109]
#define XTP  14
#define YEW  107
#define YEH  112
#define XEW  144
#define XEH  144
#define QP   9800          // dist plane pitch (98 rows x 100)

// ---- ws layout (float units) ----
#define OFF_CV   8241856ull                 // align64(841*9800); candidates QN*4*8
#define OFF_CI   (OFF_CV + 307328ull)
#define OFF_XT   (OFF_CI + 307328ull)       // bf16 x: 124*124*16 ushort = 123008 fl
#define OFF_YEP  (OFF_XT + 123072ull)
#define OFF_XEP  (OFF_YEP + 95872ull)
// end = OFF_XEP + 165888 = 9,241,344 floats = 37 MB

__device__ __forceinline__ int imin(int a, int b){ return a<b?a:b; }
__device__ __forceinline__ int imax(int a, int b){ return a>b?a:b; }
__device__ __forceinline__ unsigned short f2bf(float f){
    unsigned u = __float_as_uint(f);
    return (unsigned short)((u + 0x7fffu + ((u >> 16) & 1u)) >> 16);
}

// ---- K0: pack x -> bf16 xTb[124][124][16]; ye -> yeP[112][107][8]; xe -> xeP[144][144][8]
__global__ __launch_bounds__(256) void k_prep(const float* __restrict__ x,
                                              const float* __restrict__ xe,
                                              const float* __restrict__ ye,
                                              unsigned short* __restrict__ xTb,
                                              float* __restrict__ xeP,
                                              float* __restrict__ yeP) {
    int t = blockIdx.x*256 + threadIdx.x;
    if (t < XTW*XTW) {
        int u = t / XTW, v = t % XTW;
        int ui = u - XTP, vi = v - XTP;
        bool inb = ((unsigned)ui < (unsigned)IH) && ((unsigned)vi < (unsigned)IW);
        int off = inb ? (ui*IW + vi) : 0;
        unsigned d[8];
        #pragma unroll
        for (int j = 0; j < 8; ++j) {
            float a = inb ? x[(2*j+0)*IH*IW + off] : 0.f;
            float b = inb ? x[(2*j+1)*IH*IW + off] : 0.f;
            d[j] = (unsigned)f2bf(a) | ((unsigned)f2bf(b) << 16);
        }
        uint4* dst = (uint4*)(xTb + (size_t)t*CH);
        dst[0] = make_uint4(d[0], d[1], d[2], d[3]);
        dst[1] = make_uint4(d[4], d[5], d[6], d[7]);
        return;
    }
    t -= XTW*XTW;
    if (t < YEH*YEW) {
        int i = t / YEW, j = t % YEW;
        bool inb = ((unsigned)(i-6) < (unsigned)IH) && ((unsigned)(j-6) < (unsigned)IW);
        int off = inb ? ((i-6)*IW + (j-6)) : 0;
        float4* dst = (float4*)(yeP + (size_t)t*CE);
        #pragma unroll
        for (int c4 = 0; c4 < 2; ++c4) {
            float4 val;
            val.x = inb ? ye[(c4*4+0)*IH*IW + off] : 0.f;
            val.y = inb ? ye[(c4*4+1)*IH*IW + off] : 0.f;
            val.z = inb ? ye[(c4*4+2)*IH*IW + off] : 0.f;
            val.w = inb ? ye[(c4*4+3)*IH*IW + off] : 0.f;
            dst[c4] = val;
        }
        return;
    }
    t -= YEH*YEW;
    if (t < XEH*XEW) {
        int i = t / XEW, j = t % XEW;
        bool inb = ((unsigned)(i-20) < (unsigned)IH) && ((unsigned)(j-20) < (unsigned)IW);
        int off = inb ? ((i-20)*IW + (j-20)) : 0;
        float4* dst = (float4*)(xeP + (size_t)t*CE);
        #pragma unroll
        for (int c4 = 0; c4 < 2; ++c4) {
            float4 val;
            val.x = inb ? xe[(c4*4+0)*IH*IW + off] : 0.f;
            val.y = inb ? xe[(c4*4+1)*IH*IW + off] : 0.f;
            val.z = inb ? xe[(c4*4+2)*IH*IW + off] : 0.f;
            val.w = inb ? xe[(c4*4+3)*IH*IW + off] : 0.f;
            dst[c4] = val;
        }
    }
}

// ---- K1: distances, barrier-free wave-private, DEFERRED phase-C (dbuf LDS) ----
// block = (dy-group of 4, dx, 25-row strip). grid = 8*29*4 = 928, 128 thr.
// Phase C at step S reads the LDS row buffer written at step S-1 (other
// buffer of the pair), and is emitted FIRST in program order so its ds_read
// overlaps this step's VALU + ds_write. Output row y0 = S-10.
__global__ __launch_bounds__(128, 4) void k_dist(const float* __restrict__ xeP,
                                                 const float* __restrict__ yeP,
                                                 float* __restrict__ dist) {
    __shared__ float cs[2][2][4][72];    // [buf][wave][dyi][col] 4.6 KB

    int b     = blockIdx.x;
    int dx_i  = b % 29;
    int rem   = b / 29;
    int strip = rem & 3;
    int dyg   = rem >> 2;                // 0..7
    int y0s   = strip * 25;
    int tid   = threadIdx.x;
    int wid   = tid >> 6;
    int lane  = tid & 63;
    int col   = wid ? (43 + lane) : lane;
    int widx  = lane + (wid ? 3 : 0);

    int nun   = wid ? 12 : 13;
    int dyi_c = imin(lane / nun, 3);
    int u     = lane - dyi_c * nun;
    bool cact = lane < nun * 4;
    int x0u   = wid ? (52 + 4*u) : (4*u);
    bool full4 = (wid == 0) || (u < 11);
    const float* rdp = &cs[0][wid][dyi_c][ wid ? (12 + 4*u) : (4*u) ];
    int plane = dyg*4 + dyi_c;
    bool plane_ok = cact && (plane <= 28);
    int dy_c  = plane - 14;
    int dx    = dx_i - 14;
    bool selfd = (dy_c == 0) && (dx == 0);
    bool okx0 = (unsigned)(x0u+0+dx) < 98u;
    bool okx1 = (unsigned)(x0u+1+dx) < 98u;
    bool okx2 = (unsigned)(x0u+2+dx) < 98u;
    bool okx3 = (unsigned)(x0u+3+dx) < 98u;
    float* dout = dist + (size_t)(imin(plane,28)*29 + dx_i)*QP + x0u;

    const size_t xstep = (size_t)XEW*CE, ystep = (size_t)YEW*CE;
    const float* xload = xeP + ((size_t)(y0s + dyg*4)*XEW + (col + dx_i))*CE;
    const float* yload = yeP + ((size_t)y0s*YEW + col)*CE;

    float4 xr[5][2];
    #pragma unroll
    for (int r = 0; r < 4; ++r) {
        xr[r][0] = ((const float4*)xload)[0];
        xr[r][1] = ((const float4*)xload)[1];
        xload += xstep;
    }
    float wsum[4] = {0.f,0.f,0.f,0.f};
    float hist[4][10];

// phase C (deferred): consumes buffer (S-1)&1, output row y0 = S-10
#define PHC(S) \
    if ((S) >= 10 && plane_ok) { \
        int y0 = y0s + (S) - 10; \
        if (y0 < 98) { \
            const float* bse = rdp + (((S)-1)&1)*576; \
            float v0=bse[0], v1=bse[1], v2=bse[2], v3=bse[3]; \
            float v4=bse[4], v5=bse[5], v6=bse[6], v7=bse[7]; \
            float v8=bse[8], v9=bse[9], v10=bse[10], v11=bse[11], v12=bse[12]; \
            float s0 = ((v0+v1)+(v2+v3)) + ((v4+v5)+(v6+v7)) + (v8+v9); \
            float s1 = s0 - v0 + v10; \
            float s2 = s1 - v1 + v11; \
            float s3 = s2 - v2 + v12; \
            bool okr = ((unsigned)(y0 + dy_c) < 98u) && !selfd; \
            float4 o; \
            o.x = (okr && okx0) ? s0 : 1e10f; \
            o.y = (okr && okx1) ? s1 : 1e10f; \
            o.z = (okr && okx2) ? s2 : 1e10f; \
            o.w = (okr && okx3) ? s3 : 1e10f; \
            if (full4) *(float4*)(dout + y0*100) = o; \
            else       *(float2*)(dout + y0*100) = make_float2(o.x, o.y); \
        } \
    }

// vertical pass: stream rows, write this step's 10-row sums to buffer S&1
#define VERT(S) \
    if ((S) < 34) { \
        float4 xna = ((const float4*)xload)[0]; \
        float4 xnb = ((const float4*)xload)[1]; \
        xload += xstep; \
        float4 ya  = ((const float4*)yload)[0]; \
        float4 yb  = ((const float4*)yload)[1]; \
        yload += ystep; \
        xr[((S)+4)%5][0] = xna; xr[((S)+4)%5][1] = xnb; \
        _Pragma("unroll") \
        for (int dyi = 0; dyi < 4; ++dyi) { \
            float4 xa = xr[((S)+dyi)%5][0]; \
            float4 xb = xr[((S)+dyi)%5][1]; \
            float d0=ya.x-xa.x, d1=ya.y-xa.y, d2=ya.z-xa.z, d3=ya.w-xa.w; \
            float d4=yb.x-xb.x, d5=yb.y-xb.y, d6=yb.z-xb.z, d7=yb.w-xb.w; \
            float a = d0*d0; \
            a=fmaf(d1,d1,a); a=fmaf(d2,d2,a); a=fmaf(d3,d3,a); \
            a=fmaf(d4,d4,a); a=fmaf(d5,d5,a); a=fmaf(d6,d6,a); \
            a=fmaf(d7,d7,a); \
            float w = wsum[dyi] + a; \
            if ((S) >= 10) w -= hist[dyi][(S)%10]; \
            wsum[dyi] = w; \
            hist[dyi][(S)%10] = a; \
            cs[(S)&1][wid][dyi][widx] = w; \
        } \
    }

#define DSTEP(S) { PHC(S) VERT(S) }

    DSTEP(0)  DSTEP(1)  DSTEP(2)  DSTEP(3)  DSTEP(4)
    DSTEP(5)  DSTEP(6)  DSTEP(7)  DSTEP(8)  DSTEP(9)
    DSTEP(10) DSTEP(11) DSTEP(12) DSTEP(13) DSTEP(14)
    DSTEP(15) DSTEP(16) DSTEP(17) DSTEP(18) DSTEP(19)
    DSTEP(20) DSTEP(21) DSTEP(22) DSTEP(23) DSTEP(24)
    DSTEP(25) DSTEP(26) DSTEP(27) DSTEP(28) DSTEP(29)
    DSTEP(30) DSTEP(31) DSTEP(32) DSTEP(33) DSTEP(34)
#undef DSTEP
#undef VERT
#undef PHC
}

// ---- K2: stage-A top-7 per (query, displacement-quarter). grid 151*4 ----
__global__ __launch_bounds__(256) void k_topkA(const float* __restrict__ dist,
                                               float* __restrict__ cv, int* __restrict__ ci) {
    __shared__ float lv[3*64*8];
    __shared__ int   lix[3*64*8];
    int wv = threadIdx.x >> 6, ln = threadIdx.x & 63;
    int qb = blockIdx.x % 151;
    int rg = blockIdx.x / 151;           // 0..3
    int q  = qb*64 + ln;
    int qq = q < QN ? q : QN-1;
    int y0 = qq / 98, x0 = qq - y0*98;
    int off = y0*100 + x0;

    int rbase = rg*210 + (rg > 0 ? 1 : 0);   // 0,211,421,631
    int ndr   = (rg == 0) ? 211 : 210;
    int s0 = rbase + wv*53;
    int s1 = imin(rbase + ndr, s0 + 53);

    float ld[KNN]; int li[KNN];
    #pragma unroll
    for (int k = 0; k < KNN; ++k) { ld[k] = 1e30f; li[k] = -1; }

    auto INS = [&](float v, int dsp) {
        float cvv = v; int cii = dsp;
        #pragma unroll
        for (int k = 0; k < KNN; ++k) {
            bool sw = cvv < ld[k];
            float tf = ld[k]; int ti = li[k];
            ld[k] = sw ? cvv : tf;  li[k] = sw ? cii : ti;
            cvv   = sw ? tf : cvv;  cii   = sw ? ti : cii;
        }
    };

    #pragma unroll 4
    for (int dd = s0; dd < s1; ++dd)
        INS(dist[(size_t)dd*QP + off], dd);

    if (wv) {
        int bse = ((wv-1)*64 + ln)*8;
        #pragma unroll
        for (int r = 0; r < KNN; ++r) { lv[bse+r] = ld[r]; lix[bse+r] = li[r]; }
    }
    __syncthreads();
    if (wv == 0 && q < QN) {
        #pragma unroll
        for (int w = 0; w < 3; ++w) {
            int bse = (w*64 + ln)*8;
            #pragma unroll
            for (int r = 0; r < KNN; ++r) INS(lv[bse+r], lix[bse+r]);
        }
        #pragma unroll
        for (int r = 0; r < KNN; ++r) {
            cv[(q*4 + rg)*8 + r] = ld[r];
            ci[(q*4 + rg)*8 + r] = li[r];
        }
    }
}

// ---- K3: merge+softmax staging, then bf16 gather aggregation ----
// block = 4x4 pixel tile, 256 thr = 8 (oy,ox)-groups x (16 px x 2 ch-halves)
__global__ __launch_bounds__(256) void k_agg(const float* __restrict__ x,
                                             const unsigned short* __restrict__ xTb,
                                             const float* __restrict__ cv,
                                             const int* __restrict__ ci,
                                             float* __restrict__ out) {
    __shared__ float2 lw[169*7];      // (w, delta_ushort_units) per halo query
    __shared__ float  red[7][8][32];  // og 1..7 partials, conflict-free layout
    int tid = threadIdx.x;
    int tb  = blockIdx.x;
    int ai0 = (tb / 24) * 4, bi0 = (tb % 24) * 4;

    // stage: per halo query merge 28 candidates -> top7 -> softmax -> (w, dl)
    if (tid < 169) {
        int lqi = tid / 13, lqj = tid - lqi*13;
        int qi = ai0 - 3 + lqi, qj = bi0 - 3 + lqj;
        bool ok = ((unsigned)qi < 98u) && ((unsigned)qj < 98u);
        float ld[KNN]; int li[KNN];
        #pragma unroll
        for (int k = 0; k < KNN; ++k) { ld[k] = 1e30f; li[k] = -1; }
        if (ok) {
            int q = qi*98 + qj;
            #pragma unroll
            for (int rg = 0; rg < 4; ++rg) {
                #pragma unroll
                for (int r = 0; r < KNN; ++r) {
                    float v  = cv[(q*4 + rg)*8 + r];
                    int dsp  = ci[(q*4 + rg)*8 + r];
                    float cvv = v; int cii = dsp;
                    #pragma unroll
                    for (int k = 0; k < KNN; ++k) {
                        bool sw = cvv < ld[k];
                        float tf = ld[k]; int ti = li[k];
                        ld[k] = sw ? cvv : tf;  li[k] = sw ? cii : ti;
                        cvv   = sw ? tf : cvv;  cii   = sw ? ti : cii;
                    }
                }
            }
            float e[KNN]; float ssum = 0.f;
            #pragma unroll
            for (int r = 0; r < KNN; ++r) { e[r] = __expf(ld[0] - ld[r]); ssum += e[r]; }
            float inv = 1.f / ssum;
            #pragma unroll
            for (int r = 0; r < KNN; ++r) {
                int dsp = li[r];
                int dyk = dsp / WSZ - RR, dxk = dsp % WSZ - RR;
                lw[tid*7 + r] = make_float2(e[r]*inv,
                                            __int_as_float((dyk*XTW + dxk)*CH));
            }
        } else {
            #pragma unroll
            for (int r = 0; r < KNN; ++r) lw[tid*7 + r] = make_float2(0.f, 0.f);
        }
    }
    __syncthreads();

    int og   = tid >> 5;          // 0..7 position groups
    int rem  = tid & 31;
    int half = rem & 1;           // channel half (0: ch0-7, 1: ch8-15)
    int pl   = rem >> 1;          // 0..15 pixel
    int py   = pl >> 2, px = pl & 3;
    int ai = ai0 + py, bi = bi0 + px;
    int baseu = ((ai + XTP)*XTW + (bi + XTP))*CH + half*8;

    float acc[8] = {0.f,0.f,0.f,0.f,0.f,0.f,0.f,0.f};
    #pragma unroll
    for (int c = 0; c < 13; ++c) {
        int u = og*13 + c;
        if (u >= 100) break;
        int oy = u / 10, ox = u - oy*10;
        int lq = (py + 9 - oy)*13 + (px + 9 - ox);
        const float2* f2p = lw + lq*7;
        #pragma unroll
        for (int k = 0; k < KNN; ++k) {
            float2 wd = f2p[k];
            float w = wd.x;
            int dl = __float_as_int(wd.y);
            const uint4 g = *(const uint4*)(xTb + baseu + dl);
            acc[0] = fmaf(w, __uint_as_float(g.x << 16),          acc[0]);
            acc[1] = fmaf(w, __uint_as_float(g.x & 0xffff0000u),  acc[1]);
            acc[2] = fmaf(w, __uint_as_float(g.y << 16),          acc[2]);
            acc[3] = fmaf(w, __uint_as_float(g.y & 0xffff0000u),  acc[3]);
            acc[4] = fmaf(w, __uint_as_float(g.z << 16),          acc[4]);
            acc[5] = fmaf(w, __uint_as_float(g.z & 0xffff0000u),  acc[5]);
            acc[6] = fmaf(w, __uint_as_float(g.w << 16),          acc[6]);
            acc[7] = fmaf(w, __uint_as_float(g.w & 0xffff0000u),  acc[7]);
        }
    }

    if (og) {
        #pragma unroll
        for (int c = 0; c < 8; ++c) red[og-1][c][rem] = acc[c];
    }
    __syncthreads();
    if (og == 0) {
        #pragma unroll
        for (int w = 0; w < 7; ++w)
            #pragma unroll
            for (int c = 0; c < 8; ++c) acc[c] += red[w][c][rem];

        int i = ai + 6, j = bi + 6;
        float cr = (float)(imin(i, 97) - imax(i - 9, 0) + 1);
        float cc = (float)(imin(j, 97) - imax(j - 9, 0) + 1);
        float inv = 1.f / (cr * cc);
        int p = ai*IW + bi;
        #pragma unroll
        for (int c = 0; c < 8; ++c) {
            int ch = half*8 + c;
            float xv = x[ch*IH*IW + p];           // exact f32 copy of y
            out[ch*IH*IW + p] = xv;
            out[(16 + ch)*IH*IW + p] = acc[c]*inv - xv;
        }
    }
}

extern "C" void kernel_launch(void* const* d_in, const int* in_sizes, int n_in,
                              void* d_out, int out_size, void* d_ws, size_t ws_size,
                              hipStream_t stream) {
    const float* x  = (const float*)d_in[0];
    const float* xe = (const float*)d_in[1];
    const float* ye = (const float*)d_in[2];
    float* out = (float*)d_out;
    float* ws  = (float*)d_ws;

    float* dist = ws;
    float* cv   = ws + OFF_CV;
    int*   ci   = (int*)(ws + OFF_CI);
    unsigned short* xTb = (unsigned short*)(ws + OFF_XT);
    float* yeP  = ws + OFF_YEP;
    float* xeP  = ws + OFF_XEP;

    {
        int total = XTW*XTW + YEH*YEW + XEH*XEW;
        hipLaunchKernelGGL(k_prep, dim3((total + 255)/256), dim3(256), 0, stream,
                           x, xe, ye, xTb, xeP, yeP);
    }
    hipLaunchKernelGGL(k_dist,  dim3(8*29*4), dim3(128), 0, stream, xeP, yeP, dist);
    hipLaunchKernelGGL(k_topkA, dim3(151*4), dim3(256), 0, stream, dist, cv, ci);
    hipLaunchKernelGGL(k_agg,   dim3(24*24), dim3(256), 0, stream, x, xTb, cv, ci, out);
}